// Round 4
// baseline (386.149 us; speedup 1.0000x reference)
//
#include <hip/hip_runtime.h>
#include <math.h>

#define B_N 16384
#define C_N 250
#define D_N 2048
#define CP  256

// ---- workspace layout (float offsets) ----
// zeroed region (one small hipMemsetAsync):
#define OFF_PP     0          // 62500
#define OFF_SCAL   62500      // 64 (incl tail counter u[8])
#define OFF_SSP    62564      // 256 per-class |cent|^2 partial sums
#define OFF_GC     62820      // 256 per-class quarter counters (uint)
#define ZERO_N     63076
// non-zeroed (fully written before read):
#define OFF_COUNTS 63076      // 256
#define OFF_OFFG   63332      // 260 ints (off[257])
#define OFF_BH     63592      // 16384 ints
#define OFF_SORT   79976      // 16384 ints
#define OFF_CENT   96360      // 524288
#define OFF_GRAMP  620648     // 1048576 = 16 slices x 256x256
#define OFF_C2RAW  1669224    // 256
#define OFF_C2N    1669480    // 256
#define OFF_CINV   1669736    // 256
#define OFF_PSN    1669992    // 65536 = 4 quarters x 16384
#define OFF_CENTNB 1735528    // 262144 floats = 256x2048 bf16 (UNnormalized mean)
#define T1_END     1997672    // ~8 MB
#define OFF_EBF    1997672    // 16777216 floats = 16384x2048 bf16 (UNnormalized)
#define T2_END     18774888   // ~75 MB

// scalar slots: float: 0=ce_sum 1=S1(pd^2) 2=margin_sum 5=n_upper 6=n_pairs
//               9=S2(pd*M) 10=S3(M^2)
// uint: 3=maxM bits, 4=pmax bits, 7=npresent, 8=tail counter

typedef __bf16 bf16x8 __attribute__((ext_vector_type(8)));
typedef float  f32x4  __attribute__((ext_vector_type(4)));

__device__ __forceinline__ unsigned short bfbits(float x){
  unsigned u = __float_as_uint(x);
  return (unsigned short)((u + 0x7FFFu + ((u>>16)&1u)) >> 16);  // RNE
}

__device__ __forceinline__ void gload_lds16(const void* g, void* l){
  __builtin_amdgcn_global_load_lds(
      (const __attribute__((address_space(1))) unsigned*)g,
      (__attribute__((address_space(3))) unsigned*)l, 16, 0, 0);
}

__device__ __forceinline__ float warpSum(float v){
#pragma unroll
  for(int o=32;o;o>>=1) v += __shfl_xor(v,o,64);
  return v;
}
__device__ __forceinline__ float warpMax(float v){
#pragma unroll
  for(int o=32;o;o>>=1) v = fmaxf(v, __shfl_xor(v,o,64));
  return v;
}
__device__ __forceinline__ float blockSum256(float v){
  __shared__ float s[4];
  int lane = threadIdx.x & 63, w = threadIdx.x >> 6;
  v = warpSum(v);
  __syncthreads();
  if(lane==0) s[w]=v;
  __syncthreads();
  return s[0]+s[1]+s[2]+s[3];
}
__device__ __forceinline__ float blockMax256(float v){
  __shared__ float s[4];
  int lane = threadIdx.x & 63, w = threadIdx.x >> 6;
  v = warpMax(v);
  __syncthreads();
  if(lane==0) s[w]=v;
  __syncthreads();
  return fmaxf(fmaxf(s[0],s[1]), fmaxf(s[2],s[3]));
}

// ---------------- fat1: CE (blocks 0..1023) + hist+maxM+pads (1024..1087) ---
__global__ __launch_bounds__(256) void tgl_cehist(const float* __restrict__ logits,
                                                  const int* __restrict__ labels,
                                                  const float* __restrict__ M,
                                                  int* __restrict__ bh,
                                                  unsigned short* __restrict__ centnb,
                                                  float* __restrict__ scal){
  if(blockIdx.x >= 1024){
    __shared__ int h[256];
    unsigned* scal_u = (unsigned*)scal;
    int b = blockIdx.x - 1024, t = threadIdx.x;
    h[t] = 0;
    __syncthreads();
    atomicAdd(&h[labels[b*256 + t]], 1);
    __syncthreads();
    bh[b*256 + t] = h[t];
    // fused max(M) chunk (needed by tail2's margin mask)
    float lm = 0.f;
    int i1 = b*977 + 977; if(i1 > C_N*C_N) i1 = C_N*C_N;
    for(int i = b*977 + t; i < i1; i += 256) lm = fmaxf(lm, M[i]);
    lm = blockMax256(lm);
    if(t==0) atomicMax(&scal_u[3], __float_as_uint(lm));
    // centnb bf16 zero-pad rows 250..255 (margin B-staging reads 256 rows)
    if(b < 6){
      for(int d=t; d<D_N; d+=256) centnb[(size_t)(C_N+b)*D_N + d] = 0;
    }
    return;
  }
  int lane = threadIdx.x & 63, w = threadIdx.x >> 6;
  float lsum = 0.f;
#pragma unroll
  for(int u=0; u<4; ++u){
    int r = blockIdx.x*16 + w*4 + u;
    const float* row = logits + (size_t)r*C_N;
    float x0 = (lane     < C_N) ? row[lane]     : -1e30f;
    float x1 = (lane+64  < C_N) ? row[lane+64]  : -1e30f;
    float x2 = (lane+128 < C_N) ? row[lane+128] : -1e30f;
    float x3 = (lane+192 < C_N) ? row[lane+192] : -1e30f;
    float mx = warpMax(fmaxf(fmaxf(x0,x1), fmaxf(x2,x3)));
    float e = 0.f;
    if(lane     < C_N) e += expf(x0-mx);
    if(lane+64  < C_N) e += expf(x1-mx);
    if(lane+128 < C_N) e += expf(x2-mx);
    if(lane+192 < C_N) e += expf(x3-mx);
    e = warpSum(e);
    if(lane==0){
      int l = labels[r];
      lsum += -(row[l] - mx - logf(e));
    }
  }
  float tot = blockSum256(lsum);
  if(threadIdx.x==0) atomicAdd(&scal[0], tot);
}

// ---------------- scatter2: per-block re-scan of bh + scatter (scan fused) --
__global__ __launch_bounds__(256) void tgl_scatter(const int* __restrict__ labels,
                                                   const int* __restrict__ bh,
                                                   int* __restrict__ offg,
                                                   float* __restrict__ counts,
                                                   int* __restrict__ sorted){
  __shared__ int ps[256];
  __shared__ int lofs[256];
  int t = threadIdx.x, b = blockIdx.x;
  int run = 0, locb = 0;
#pragma unroll
  for(int b2=0;b2<64;b2++){
    int h = bh[b2*256 + t];
    if(b2 < b) locb += h;
    run += h;
  }
  ps[t] = run;
  __syncthreads();
  for(int o=1;o<256;o<<=1){
    int v = (t>=o) ? ps[t-o] : 0;
    __syncthreads();
    ps[t] += v;
    __syncthreads();
  }
  int excl = ps[t] - run;
  if(b==0){
    offg[t] = excl;
    if(t==255) offg[256] = ps[255];
    counts[t] = (float)run;
  }
  lofs[t] = excl + locb;
  __syncthreads();
  int r = b*256 + t;
  int pos = atomicAdd(&lofs[labels[r]], 1);
  sorted[pos] = r;
}

// ---------------- gather2: segment sum + FUSED per-class finalize ----------
// Quarter blocks write cent = mean (divided by count) and centnb = bf16(mean).
// Class norm factor (cinv) handled as a scalar in margin's epilogue, so the
// last-of-4 block only finalizes scalars (ssp counter pattern, like tail2).
template<bool EBF>
__global__ __launch_bounds__(256) void tgl_gather(const float* __restrict__ emb,
                                                  const int* __restrict__ sorted,
                                                  const int* __restrict__ offg,
                                                  float* __restrict__ cent,
                                                  float* __restrict__ psn,
                                                  unsigned short* __restrict__ ebf,
                                                  unsigned short* __restrict__ centnb,
                                                  float* __restrict__ ssp,
                                                  unsigned* __restrict__ gc,
                                                  float* __restrict__ c2raw,
                                                  float* __restrict__ c2n,
                                                  float* __restrict__ cinv,
                                                  unsigned* __restrict__ npresent){
  __shared__ float red[2048];            // 8 KB
  __shared__ int lrows[256];
  int t = threadIdx.x, l = t & 63, w = t >> 6;
  int c = blockIdx.x, h = blockIdx.y;
  int d0 = h*512;
  int off = offg[c];
  int cnt = offg[c+1] - off;
  const int* rows = sorted + off;
  for(int i=t; i<cnt && i<256; i+=256) lrows[i] = rows[i];
  __syncthreads();
  f32x4 acc0 = {}, acc1 = {};
  int k = w;
  for(; k+4 < cnt; k += 8){
    int row0 = (k   < 256) ? lrows[k]   : rows[k];
    int row1 = (k+4 < 256) ? lrows[k+4] : rows[k+4];
    const float* rp0 = emb + (size_t)row0*D_N + d0;
    const float* rp1 = emb + (size_t)row1*D_N + d0;
    float4 a0 = *(const float4*)&rp0[l*4];
    float4 a1 = *(const float4*)&rp0[256 + l*4];
    float4 b0 = *(const float4*)&rp1[l*4];
    float4 b1 = *(const float4*)&rp1[256 + l*4];
    float sq0 = a0.x*a0.x+a0.y*a0.y+a0.z*a0.z+a0.w*a0.w
              + a1.x*a1.x+a1.y*a1.y+a1.z*a1.z+a1.w*a1.w;
    float sq1 = b0.x*b0.x+b0.y*b0.y+b0.z*b0.z+b0.w*b0.w
              + b1.x*b1.x+b1.y*b1.y+b1.z*b1.z+b1.w*b1.w;
    sq0 = warpSum(sq0); sq1 = warpSum(sq1);
    if(l==0){ psn[(size_t)h*B_N + row0] = sq0; psn[(size_t)h*B_N + row1] = sq1; }
    if constexpr(EBF){
      unsigned short* o0 = ebf + (size_t)row0*D_N + d0;
      unsigned short* o1 = ebf + (size_t)row1*D_N + d0;
      ushort4 hb;
      hb.x=bfbits(a0.x); hb.y=bfbits(a0.y); hb.z=bfbits(a0.z); hb.w=bfbits(a0.w);
      *(ushort4*)&o0[l*4] = hb;
      hb.x=bfbits(a1.x); hb.y=bfbits(a1.y); hb.z=bfbits(a1.z); hb.w=bfbits(a1.w);
      *(ushort4*)&o0[256 + l*4] = hb;
      hb.x=bfbits(b0.x); hb.y=bfbits(b0.y); hb.z=bfbits(b0.z); hb.w=bfbits(b0.w);
      *(ushort4*)&o1[l*4] = hb;
      hb.x=bfbits(b1.x); hb.y=bfbits(b1.y); hb.z=bfbits(b1.z); hb.w=bfbits(b1.w);
      *(ushort4*)&o1[256 + l*4] = hb;
    }
    acc0[0]+=a0.x+b0.x; acc0[1]+=a0.y+b0.y; acc0[2]+=a0.z+b0.z; acc0[3]+=a0.w+b0.w;
    acc1[0]+=a1.x+b1.x; acc1[1]+=a1.y+b1.y; acc1[2]+=a1.z+b1.z; acc1[3]+=a1.w+b1.w;
  }
  if(k < cnt){
    int row0 = (k < 256) ? lrows[k] : rows[k];
    const float* rp0 = emb + (size_t)row0*D_N + d0;
    float4 a0 = *(const float4*)&rp0[l*4];
    float4 a1 = *(const float4*)&rp0[256 + l*4];
    float sq0 = a0.x*a0.x+a0.y*a0.y+a0.z*a0.z+a0.w*a0.w
              + a1.x*a1.x+a1.y*a1.y+a1.z*a1.z+a1.w*a1.w;
    sq0 = warpSum(sq0);
    if(l==0) psn[(size_t)h*B_N + row0] = sq0;
    if constexpr(EBF){
      unsigned short* o0 = ebf + (size_t)row0*D_N + d0;
      ushort4 hb;
      hb.x=bfbits(a0.x); hb.y=bfbits(a0.y); hb.z=bfbits(a0.z); hb.w=bfbits(a0.w);
      *(ushort4*)&o0[l*4] = hb;
      hb.x=bfbits(a1.x); hb.y=bfbits(a1.y); hb.z=bfbits(a1.z); hb.w=bfbits(a1.w);
      *(ushort4*)&o0[256 + l*4] = hb;
    }
    acc0[0]+=a0.x; acc0[1]+=a0.y; acc0[2]+=a0.z; acc0[3]+=a0.w;
    acc1[0]+=a1.x; acc1[1]+=a1.y; acc1[2]+=a1.z; acc1[3]+=a1.w;
  }
  __syncthreads();
  *(f32x4*)&red[w*512 + l*4]       = acc0;
  *(f32x4*)&red[w*512 + 256 + l*4] = acc1;
  __syncthreads();
  float ic = 1.f / fmaxf((float)cnt, 1.f);
  float myss = 0.f;
  if(t < 128){
    f32x4 s = *(f32x4*)&red[t*4];
#pragma unroll
    for(int ww=1; ww<4; ww++){
      f32x4 r2 = *(f32x4*)&red[ww*512 + t*4];
      s[0]+=r2[0]; s[1]+=r2[1]; s[2]+=r2[2]; s[3]+=r2[3];
    }
    s[0]*=ic; s[1]*=ic; s[2]*=ic; s[3]*=ic;
    *(f32x4*)&cent[(size_t)c*D_N + d0 + t*4] = s;
    ushort4 hb;
    hb.x=bfbits(s[0]); hb.y=bfbits(s[1]); hb.z=bfbits(s[2]); hb.w=bfbits(s[3]);
    *(ushort4*)&centnb[(size_t)c*D_N + d0 + t*4] = hb;
    myss = s[0]*s[0]+s[1]*s[1]+s[2]*s[2]+s[3]*s[3];
  }
  float ss = blockSum256(myss);
  if(t==0){
    atomicAdd(&ssp[c], ss);
    __threadfence();
    unsigned old = atomicAdd(&gc[c], 1u);
    if(old == 3u){                         // last of 4 quarters: scalars only
      float sst = atomicAdd(&ssp[c], 0.f);
      c2raw[c] = sst;
      float inv = 1.f / fmaxf(sqrtf(sst), 1e-12f);
      cinv[c] = inv;
      c2n[c] = sst*inv*inv;
      if(cnt > 0) atomicAdd(npresent, 1u);
    }
  }
}

// ---------------- centroid Gram (k-split 16, non-atomic partial slabs) -------
__global__ __launch_bounds__(256) void tgl_gram(const float* __restrict__ cent,
                                                float* __restrict__ gramp){
  __shared__ float at[64][36];
  __shared__ float bt[64][36];
  int t = threadIdx.x, tx = t & 15, ty = t >> 4;
  int i0 = blockIdx.x*64, j0 = blockIdx.y*64, k0 = blockIdx.z*128;
  float acc[4][4] = {};
  for(int kk=k0; kk<k0+128; kk+=32){
    __syncthreads();
#pragma unroll
    for(int u=0;u<2;u++){
      int v = t + u*256; int r = v>>3, q = (v&7)*4;
      float4 a = (i0+r < C_N) ? *(const float4*)&cent[(size_t)(i0+r)*D_N + kk + q] : make_float4(0,0,0,0);
      *(float4*)&at[r][q] = a;
      float4 b = (j0+r < C_N) ? *(const float4*)&cent[(size_t)(j0+r)*D_N + kk + q] : make_float4(0,0,0,0);
      *(float4*)&bt[r][q] = b;
    }
    __syncthreads();
#pragma unroll
    for(int kq=0;kq<8;kq++){
      float4 a[4], b[4];
#pragma unroll
      for(int i=0;i<4;i++) a[i] = *(float4*)&at[ty*4+i][kq*4];
#pragma unroll
      for(int j=0;j<4;j++) b[j] = *(float4*)&bt[tx+16*j][kq*4];
#pragma unroll
      for(int i=0;i<4;i++)
#pragma unroll
        for(int j=0;j<4;j++)
          acc[i][j] += a[i].x*b[j].x + a[i].y*b[j].y + a[i].z*b[j].z + a[i].w*b[j].w;
    }
  }
  float* slab = gramp + (size_t)blockIdx.z*65536;
#pragma unroll
  for(int i=0;i<4;i++)
#pragma unroll
    for(int j=0;j<4;j++)
      slab[(size_t)(i0+ty*4+i)*CP + (j0+tx+16*j)] = acc[i][j];
}

// ---------------- margin GEMM: 64x256 tile, 512 thr, 3-buffer counted-vmcnt --
// T3+T4: tile k+2 staged while computing k; s_waitcnt vmcnt(5) (one stage's
// 5 gloads stay in flight across the barrier). Raw s_barrier. 256 blocks=1/CU.
// Epilogue: per-row inv_en from psn (4 loads) + per-col cinv scalar (centnb is
// the UNnormalized mean in bf16; normalization is scale-invariant in bf16).
template<bool EBF>
__global__ __launch_bounds__(512) void tgl_margin(const unsigned short* __restrict__ ebf,
                                                  const float* __restrict__ emb,
                                                  const float* __restrict__ psn,
                                                  const unsigned short* __restrict__ centnb,
                                                  const int* __restrict__ labels,
                                                  const float* __restrict__ c2n,
                                                  const float* __restrict__ cinv,
                                                  float* __restrict__ pp){
  __shared__ __align__(16) char smem[122880];  // 3 x (A 8KB + B 32KB)
  int t = threadIdx.x, w = t>>6, l = t&63;
  int wm = w>>2, wn = w&3;                     // 8 waves: 2 (M) x 4 (N), 32x64 each
  int s0 = blockIdx.x*64;

  // hoisted per-thread staging sources + LDS byte offsets (advance by kk only)
  const unsigned short* pA;
  const unsigned short* pB[4];
  int ldsA = t*16;
  int ldsB[4];
  {
    int rowA = t>>3, ksA = t&7;
    pA = ebf + (size_t)(s0+rowA)*D_N + ((ksA ^ (rowA&7))<<3);
#pragma unroll
    for(int q=0;q<4;q++){
      int s2 = q*512 + t;
      int rowB = s2>>3, ksB = s2&7;
      pB[q] = centnb + (size_t)rowB*D_N + ((ksB ^ (rowB&7))<<3);
      ldsB[q] = 8192 + s2*16;
    }
  }
  const float* pE[2]; int ldsE[2];
  if constexpr(!EBF){
#pragma unroll
    for(int q2=0;q2<2;q2++){
      int v = q2*512 + t;
      int rowE = v>>4, kqE = v&15;
      pE[q2] = emb + (size_t)(s0+rowE)*D_N + kqE*4;
      ldsE[q2] = rowE*128 + (((kqE>>1)^(rowE&7))<<4) + (kqE&1)*8;
    }
  }

  auto stage = [&](char* dst, int kk){
#pragma unroll
    for(int q=0;q<4;q++)
      gload_lds16(pB[q] + kk, dst + ldsB[q]);
    if constexpr(EBF){
      gload_lds16(pA + kk, dst + ldsA);
    } else {
#pragma unroll
      for(int q2=0;q2<2;q2++){
        float4 f = *(const float4*)(pE[q2] + kk);
        ushort4 hb;
        hb.x=bfbits(f.x); hb.y=bfbits(f.y); hb.z=bfbits(f.z); hb.w=bfbits(f.w);
        *(ushort4*)(dst + ldsE[q2]) = hb;
      }
    }
  };

  // hoisted ds_read byte offsets: A row m at m*128 ^swizzle; B at +8192
  int baseA[2], baseB[4], xofs[2];
#pragma unroll
  for(int i=0;i<2;i++)  baseA[i]  = (wm*32 + i*16 + (l&15))*128;
#pragma unroll
  for(int jj=0;jj<4;jj++) baseB[jj] = 8192 + (wn*64 + jj*16 + (l&15))*128;
#pragma unroll
  for(int s=0;s<2;s++)  xofs[s]  = ((s*4 + (l>>4)) ^ (l&7))<<4;

  char* bR = smem;              // read
  char* bN = smem + 40960;      // next (in flight)
  char* bS = smem + 81920;      // stage target
  f32x4 acc[2][4] = {};

  stage(bR, 0);
  stage(bN, 64);
  if constexpr(EBF) asm volatile("s_waitcnt vmcnt(5)" ::: "memory");
  else              asm volatile("s_waitcnt vmcnt(0) lgkmcnt(0)" ::: "memory");
  __builtin_amdgcn_s_barrier();

  for(int ks=0; ks<32; ++ks){
    if(ks < 30) stage(bS, (ks+2)*64);
#pragma unroll
    for(int s=0;s<2;s++){
      bf16x8 af[2], bfr[4];
#pragma unroll
      for(int i=0;i<2;i++)   af[i]   = *(const bf16x8*)(bR + baseA[i]  + xofs[s]);
#pragma unroll
      for(int jj=0;jj<4;jj++) bfr[jj] = *(const bf16x8*)(bR + baseB[jj] + xofs[s]);
#pragma unroll
      for(int i=0;i<2;i++)
#pragma unroll
        for(int jj=0;jj<4;jj++)
          acc[i][jj] = __builtin_amdgcn_mfma_f32_16x16x32_bf16(af[i], bfr[jj], acc[i][jj], 0,0,0);
    }
    if constexpr(EBF){
      if(ks < 30) asm volatile("s_waitcnt vmcnt(5)" ::: "memory");
      else        asm volatile("s_waitcnt vmcnt(0)" ::: "memory");
    } else {
      asm volatile("s_waitcnt vmcnt(0) lgkmcnt(0)" ::: "memory");
    }
    __builtin_amdgcn_s_barrier();
    char* tmp = bR; bR = bN; bN = bS; bS = tmp;
  }

  float c2nv[4], civ[4];
#pragma unroll
  for(int jj=0;jj<4;jj++){
    int c = wn*64 + jj*16 + (l&15);
    bool ok = c < C_N;
    c2nv[jj] = ok ? c2n[c]  : 0.f;
    civ[jj]  = ok ? cinv[c] : 0.f;
  }
#pragma unroll
  for(int i=0;i<2;i++){
#pragma unroll
    for(int r=0;r<4;r++){
      int srow = s0 + wm*32 + i*16 + (l>>4)*4 + r;
      int lab = labels[srow];
      float sn = psn[srow] + psn[B_N+srow] + psn[2*B_N+srow] + psn[3*B_N+srow];
      float inv = 1.f / fmaxf(sqrtf(sn), 1e-12f);
#pragma unroll
      for(int jj=0;jj<4;jj++){
        int c = wn*64 + jj*16 + (l&15);
        if(c < C_N){
          float dot = acc[i][jj][r]*inv*civ[jj];
          float d2 = 1.f + c2nv[jj] - 2.f*dot;
          float h = 1.2f - sqrtf(fmaxf(d2, 0.f));
          if(h > 0.f) atomicAdd(&pp[(size_t)lab*C_N + c], h);
        }
      }
    }
  }
}

// ---------------- tail2: pdist-reduce + topo (expanded) + margin + finalize --
// topo sum expanded so pmax is only needed as a final scalar:
//   Sum (pd/pmax - M/maxM)^2 = S1/pmax^2 - 2*S2/(pmax*maxM) + S3/maxM^2
__global__ __launch_bounds__(256) void tgl_tail2(const float* __restrict__ gramp,
                                                 const float* __restrict__ c2raw,
                                                 const float* __restrict__ counts,
                                                 const float* __restrict__ M,
                                                 const float* __restrict__ pp,
                                                 float* __restrict__ scal,
                                                 float* __restrict__ out){
  unsigned* scal_u = (unsigned*)scal;
  float maxM = scal[3];                 // finalized in fat1 (kernel boundaries ago)
  float inv_maxM = 1.f / maxM;
  int idx = blockIdx.x*256 + threadIdx.x;
  float s1=0.f, s2=0.f, s3=0.f, c1=0.f, sm=0.f, c2=0.f;
  if(idx < C_N*C_N){
    int i = idx / C_N, j = idx % C_N;
    float g = 0.f;
#pragma unroll
    for(int s=0; s<16; s++) g += gramp[(size_t)s*65536 + (size_t)i*CP + j];
    float ps = c2raw[i] + c2raw[j] - 2.f*g;
    float pd = sqrtf(fmaxf(ps, 0.f) + 1e-12f);
    bool both = counts[i] > 0.f && counts[j] > 0.f;
    if(both) atomicMax(&scal_u[4], __float_as_uint(pd));
    float Mv = M[idx];
    if(j > i && both){ s1 = pd*pd; s2 = pd*Mv; s3 = Mv*Mv; c1 = 1.f; }
    float Mn = Mv*inv_maxM;
    if(i != j && both && Mn < 0.3f){
      sm = pp[idx] / fmaxf(counts[i], 1.f);
      c2 = 1.f;
    }
  }
  s1 = blockSum256(s1); s2 = blockSum256(s2); s3 = blockSum256(s3);
  c1 = blockSum256(c1); sm = blockSum256(sm); c2 = blockSum256(c2);
  if(threadIdx.x==0){
    atomicAdd(&scal[1], s1); atomicAdd(&scal[9], s2); atomicAdd(&scal[10], s3);
    atomicAdd(&scal[5], c1); atomicAdd(&scal[2], sm); atomicAdd(&scal[6], c2);
    __threadfence();
    unsigned old = atomicAdd(&scal_u[8], 1u);
    if(old == gridDim.x - 1){
      float S1   = atomicAdd(&scal[1], 0.f);
      float S2b  = atomicAdd(&scal[9], 0.f);
      float S3b  = atomicAdd(&scal[10], 0.f);
      float nu   = atomicAdd(&scal[5], 0.f);
      float msum = atomicAdd(&scal[2], 0.f);
      float np   = atomicAdd(&scal[6], 0.f);
      float ce   = atomicAdd(&scal[0], 0.f) / (float)B_N;
      unsigned npr = atomicAdd(&scal_u[7], 0u);
      float pmax = __uint_as_float(atomicMax(&scal_u[4], 0u));
      float ip = 1.f / pmax;
      float tsum = fmaxf(S1*ip*ip - 2.f*S2b*ip*inv_maxM + S3b*inv_maxM*inv_maxM, 0.f);
      int gate = npr >= 2u;
      float topo   = gate ? tsum / fmaxf(nu, 1.f) : 0.f;
      float margin = (gate && np > 0.f) ? msum / fmaxf(np, 1.f) : 0.f;
      out[0] = ce + 0.1f*topo + 0.05f*margin;
      out[1] = ce;
      out[2] = topo;
      out[3] = margin;
    }
  }
}

extern "C" void kernel_launch(void* const* d_in, const int* in_sizes, int n_in,
                              void* d_out, int out_size, void* d_ws, size_t ws_size,
                              hipStream_t stream){
  const float* logits = (const float*)d_in[0];
  const int*   labels = (const int*)d_in[1];
  const float* emb    = (const float*)d_in[2];
  const float* M      = (const float*)d_in[3];
  float* out = (float*)d_out;
  float* ws  = (float*)d_ws;

  float* pp     = ws + OFF_PP;
  float* scal   = ws + OFF_SCAL;
  float* ssp    = ws + OFF_SSP;
  unsigned* gc  = (unsigned*)(ws + OFF_GC);
  float* counts = ws + OFF_COUNTS;
  int*   offg   = (int*)(ws + OFF_OFFG);
  int*   bh     = (int*)(ws + OFF_BH);
  int*   sorted = (int*)(ws + OFF_SORT);
  float* cent   = ws + OFF_CENT;
  float* gramp  = ws + OFF_GRAMP;
  float* c2raw  = ws + OFF_C2RAW;
  float* c2n    = ws + OFF_C2N;
  float* cinv   = ws + OFF_CINV;
  float* psn    = ws + OFF_PSN;
  unsigned short* centnb = (unsigned short*)(ws + OFF_CENTNB);
  unsigned short* ebf    = (unsigned short*)(ws + OFF_EBF);
  unsigned* scal_u = (unsigned*)scal;

  bool use_ebf = (ws_size / sizeof(float)) >= (size_t)T2_END;

  hipMemsetAsync(d_ws, 0, (size_t)ZERO_N*sizeof(float), stream);

  tgl_cehist<<<1088, 256, 0, stream>>>(logits, labels, M, bh, centnb, scal);
  tgl_scatter<<<64, 256, 0, stream>>>(labels, bh, offg, counts, sorted);
  {
    dim3 g(C_N, 4);
    if(use_ebf) tgl_gather<true ><<<g, 256, 0, stream>>>(emb, sorted, offg, cent, psn, ebf, centnb, ssp, gc, c2raw, c2n, cinv, &scal_u[7]);
    else        tgl_gather<false><<<g, 256, 0, stream>>>(emb, sorted, offg, cent, psn, ebf, centnb, ssp, gc, c2raw, c2n, cinv, &scal_u[7]);
  }
  {
    dim3 g(4, 4, 16);
    tgl_gram<<<g, 256, 0, stream>>>(cent, gramp);
  }
  {
    if(use_ebf) tgl_margin<true ><<<256, 512, 0, stream>>>(ebf, emb, psn, centnb, labels, c2n, cinv, pp);
    else        tgl_margin<false><<<256, 512, 0, stream>>>(ebf, emb, psn, centnb, labels, c2n, cinv, pp);
  }
  tgl_tail2<<<(C_N*C_N + 255)/256, 256, 0, stream>>>(gramp, c2raw, counts, M, pp, scal, out);
}

// Round 5
// 339.756 us; speedup vs baseline: 1.1365x; 1.1365x over previous
//
#include <hip/hip_runtime.h>
#include <math.h>

#define B_N 16384
#define C_N 250
#define D_N 2048
#define CP  256

// ---- workspace layout (float offsets) ----
// zeroed region (one small hipMemsetAsync):
#define OFF_PP     0          // 62500
#define OFF_SCAL   62500      // 64 (incl tail counter u[8])
#define ZERO_N     62564
// non-zeroed (fully written before read):
#define OFF_COUNTS 62564      // 256
#define OFF_OFFG   62820      // 260 ints (off[257])
#define OFF_BH     63080      // 16384 ints
#define OFF_SORT   79464      // 16384 ints
#define OFF_CENT   95848      // 524288
#define OFF_GRAMP  620136     // 1048576 = 16 slices x 256x256
#define OFF_C2RAW  1668712    // 256
#define OFF_C2N    1668968    // 256
#define OFF_INVEN  1669224    // 16384
#define OFF_PSN    1685608    // 65536 = 4 quarters x 16384
#define OFF_CENTNB 1751144    // 262144 floats = 256x2048 bf16 (normalized)
#define T1_END     2013288    // ~8 MB
#define OFF_EBF    2013288    // 16777216 floats = 16384x2048 bf16 (UNnormalized)
#define T2_END     18790504   // ~75 MB

// scalar slots: float: 0=ce_sum 1=S1(pd^2) 2=margin_sum 5=n_upper 6=n_pairs
//               9=S2(pd*M) 10=S3(M^2)
// uint: 3=maxM bits, 4=pmax bits, 7=npresent, 8=tail counter

typedef __bf16 bf16x8 __attribute__((ext_vector_type(8)));
typedef float  f32x4  __attribute__((ext_vector_type(4)));

__device__ __forceinline__ unsigned short bfbits(float x){
  unsigned u = __float_as_uint(x);
  return (unsigned short)((u + 0x7FFFu + ((u>>16)&1u)) >> 16);  // RNE
}

__device__ __forceinline__ void gload_lds16(const void* g, void* l){
  __builtin_amdgcn_global_load_lds(
      (const __attribute__((address_space(1))) unsigned*)g,
      (__attribute__((address_space(3))) unsigned*)l, 16, 0, 0);
}

__device__ __forceinline__ float warpSum(float v){
#pragma unroll
  for(int o=32;o;o>>=1) v += __shfl_xor(v,o,64);
  return v;
}
__device__ __forceinline__ float warpMax(float v){
#pragma unroll
  for(int o=32;o;o>>=1) v = fmaxf(v, __shfl_xor(v,o,64));
  return v;
}
__device__ __forceinline__ float blockSum256(float v){
  __shared__ float s[4];
  int lane = threadIdx.x & 63, w = threadIdx.x >> 6;
  v = warpSum(v);
  __syncthreads();
  if(lane==0) s[w]=v;
  __syncthreads();
  return s[0]+s[1]+s[2]+s[3];
}
__device__ __forceinline__ float blockMax256(float v){
  __shared__ float s[4];
  int lane = threadIdx.x & 63, w = threadIdx.x >> 6;
  v = warpMax(v);
  __syncthreads();
  if(lane==0) s[w]=v;
  __syncthreads();
  return fmaxf(fmaxf(s[0],s[1]), fmaxf(s[2],s[3]));
}

// ---------------- fat1: CE (blocks 0..1023) + hist+maxM (1024..1087) --------
__global__ __launch_bounds__(256) void tgl_cehist(const float* __restrict__ logits,
                                                  const int* __restrict__ labels,
                                                  const float* __restrict__ M,
                                                  int* __restrict__ bh,
                                                  float* __restrict__ scal){
  if(blockIdx.x >= 1024){
    __shared__ int h[256];
    unsigned* scal_u = (unsigned*)scal;
    int b = blockIdx.x - 1024, t = threadIdx.x;
    h[t] = 0;
    __syncthreads();
    atomicAdd(&h[labels[b*256 + t]], 1);
    __syncthreads();
    bh[b*256 + t] = h[t];
    // fused max(M) chunk (needed by tail2's margin mask)
    float lm = 0.f;
    int i1 = b*977 + 977; if(i1 > C_N*C_N) i1 = C_N*C_N;
    for(int i = b*977 + t; i < i1; i += 256) lm = fmaxf(lm, M[i]);
    lm = blockMax256(lm);
    if(t==0) atomicMax(&scal_u[3], __float_as_uint(lm));
    return;
  }
  int lane = threadIdx.x & 63, w = threadIdx.x >> 6;
  float lsum = 0.f;
#pragma unroll
  for(int u=0; u<4; ++u){
    int r = blockIdx.x*16 + w*4 + u;
    const float* row = logits + (size_t)r*C_N;
    float x0 = (lane     < C_N) ? row[lane]     : -1e30f;
    float x1 = (lane+64  < C_N) ? row[lane+64]  : -1e30f;
    float x2 = (lane+128 < C_N) ? row[lane+128] : -1e30f;
    float x3 = (lane+192 < C_N) ? row[lane+192] : -1e30f;
    float mx = warpMax(fmaxf(fmaxf(x0,x1), fmaxf(x2,x3)));
    float e = 0.f;
    if(lane     < C_N) e += expf(x0-mx);
    if(lane+64  < C_N) e += expf(x1-mx);
    if(lane+128 < C_N) e += expf(x2-mx);
    if(lane+192 < C_N) e += expf(x3-mx);
    e = warpSum(e);
    if(lane==0){
      int l = labels[r];
      lsum += -(row[l] - mx - logf(e));
    }
  }
  float tot = blockSum256(lsum);
  if(threadIdx.x==0) atomicAdd(&scal[0], tot);
}

// ---------------- scatter2: per-block re-scan of bh + scatter (scan fused) --
__global__ __launch_bounds__(256) void tgl_scatter(const int* __restrict__ labels,
                                                   const int* __restrict__ bh,
                                                   int* __restrict__ offg,
                                                   float* __restrict__ counts,
                                                   int* __restrict__ sorted){
  __shared__ int ps[256];
  __shared__ int lofs[256];
  int t = threadIdx.x, b = blockIdx.x;
  int run = 0, locb = 0;
#pragma unroll
  for(int b2=0;b2<64;b2++){
    int h = bh[b2*256 + t];
    if(b2 < b) locb += h;
    run += h;
  }
  ps[t] = run;
  __syncthreads();
  for(int o=1;o<256;o<<=1){
    int v = (t>=o) ? ps[t-o] : 0;
    __syncthreads();
    ps[t] += v;
    __syncthreads();
  }
  int excl = ps[t] - run;
  if(b==0){
    offg[t] = excl;
    if(t==255) offg[256] = ps[255];
    counts[t] = (float)run;
  }
  lofs[t] = excl + locb;
  __syncthreads();
  int r = b*256 + t;
  int pos = atomicAdd(&lofs[labels[r]], 1);
  sorted[pos] = r;
}

// ---------------- class-gather segment sum (sorted row list, R3-proven) -----
template<bool EBF>
__global__ __launch_bounds__(256) void tgl_gather(const float* __restrict__ emb,
                                                  const int* __restrict__ sorted,
                                                  const int* __restrict__ offg,
                                                  float* __restrict__ cent,
                                                  float* __restrict__ psn,
                                                  unsigned short* __restrict__ ebf){
  __shared__ float red[2048];            // 8 KB
  int t = threadIdx.x, l = t & 63, w = t >> 6;
  int c = blockIdx.x, h = blockIdx.y;
  int d0 = h*512;
  int off = offg[c];
  int cnt = offg[c+1] - off;
  const int* rows = sorted + off;
  f32x4 acc0 = {}, acc1 = {};
  int k = w;
  for(; k+4 < cnt; k += 8){
    int row0 = rows[k], row1 = rows[k+4];
    const float* rp0 = emb + (size_t)row0*D_N + d0;
    const float* rp1 = emb + (size_t)row1*D_N + d0;
    float4 a0 = *(const float4*)&rp0[l*4];
    float4 a1 = *(const float4*)&rp0[256 + l*4];
    float4 b0 = *(const float4*)&rp1[l*4];
    float4 b1 = *(const float4*)&rp1[256 + l*4];
    float sq0 = a0.x*a0.x+a0.y*a0.y+a0.z*a0.z+a0.w*a0.w
              + a1.x*a1.x+a1.y*a1.y+a1.z*a1.z+a1.w*a1.w;
    float sq1 = b0.x*b0.x+b0.y*b0.y+b0.z*b0.z+b0.w*b0.w
              + b1.x*b1.x+b1.y*b1.y+b1.z*b1.z+b1.w*b1.w;
    sq0 = warpSum(sq0); sq1 = warpSum(sq1);
    if(l==0){ psn[(size_t)h*B_N + row0] = sq0; psn[(size_t)h*B_N + row1] = sq1; }
    if constexpr(EBF){
      unsigned short* o0 = ebf + (size_t)row0*D_N + d0;
      unsigned short* o1 = ebf + (size_t)row1*D_N + d0;
      ushort4 hb;
      hb.x=bfbits(a0.x); hb.y=bfbits(a0.y); hb.z=bfbits(a0.z); hb.w=bfbits(a0.w);
      *(ushort4*)&o0[l*4] = hb;
      hb.x=bfbits(a1.x); hb.y=bfbits(a1.y); hb.z=bfbits(a1.z); hb.w=bfbits(a1.w);
      *(ushort4*)&o0[256 + l*4] = hb;
      hb.x=bfbits(b0.x); hb.y=bfbits(b0.y); hb.z=bfbits(b0.z); hb.w=bfbits(b0.w);
      *(ushort4*)&o1[l*4] = hb;
      hb.x=bfbits(b1.x); hb.y=bfbits(b1.y); hb.z=bfbits(b1.z); hb.w=bfbits(b1.w);
      *(ushort4*)&o1[256 + l*4] = hb;
    }
    acc0[0]+=a0.x+b0.x; acc0[1]+=a0.y+b0.y; acc0[2]+=a0.z+b0.z; acc0[3]+=a0.w+b0.w;
    acc1[0]+=a1.x+b1.x; acc1[1]+=a1.y+b1.y; acc1[2]+=a1.z+b1.z; acc1[3]+=a1.w+b1.w;
  }
  if(k < cnt){
    int row0 = rows[k];
    const float* rp0 = emb + (size_t)row0*D_N + d0;
    float4 a0 = *(const float4*)&rp0[l*4];
    float4 a1 = *(const float4*)&rp0[256 + l*4];
    float sq0 = a0.x*a0.x+a0.y*a0.y+a0.z*a0.z+a0.w*a0.w
              + a1.x*a1.x+a1.y*a1.y+a1.z*a1.z+a1.w*a1.w;
    sq0 = warpSum(sq0);
    if(l==0) psn[(size_t)h*B_N + row0] = sq0;
    if constexpr(EBF){
      unsigned short* o0 = ebf + (size_t)row0*D_N + d0;
      ushort4 hb;
      hb.x=bfbits(a0.x); hb.y=bfbits(a0.y); hb.z=bfbits(a0.z); hb.w=bfbits(a0.w);
      *(ushort4*)&o0[l*4] = hb;
      hb.x=bfbits(a1.x); hb.y=bfbits(a1.y); hb.z=bfbits(a1.z); hb.w=bfbits(a1.w);
      *(ushort4*)&o0[256 + l*4] = hb;
    }
    acc0[0]+=a0.x; acc0[1]+=a0.y; acc0[2]+=a0.z; acc0[3]+=a0.w;
    acc1[0]+=a1.x; acc1[1]+=a1.y; acc1[2]+=a1.z; acc1[3]+=a1.w;
  }
  __syncthreads();
  *(f32x4*)&red[w*512 + l*4]       = acc0;
  *(f32x4*)&red[w*512 + 256 + l*4] = acc1;
  __syncthreads();
  if(t < 128){
    f32x4 s = *(f32x4*)&red[t*4];
#pragma unroll
    for(int ww=1; ww<4; ww++){
      f32x4 r2 = *(f32x4*)&red[ww*512 + t*4];
      s[0]+=r2[0]; s[1]+=r2[1]; s[2]+=r2[2]; s[3]+=r2[3];
    }
    *(f32x4*)&cent[(size_t)c*D_N + d0 + t*4] = s;
  }
}

// ---------------- centroid finalize (+fused inv_en) ----------------
__global__ __launch_bounds__(256) void tgl_cfin(float* __restrict__ cent,
                                                const float* __restrict__ counts,
                                                const float* __restrict__ psn,
                                                float* __restrict__ inv_en,
                                                unsigned short* __restrict__ centnb,
                                                float* __restrict__ c2raw,
                                                float* __restrict__ c2n,
                                                unsigned* __restrict__ npresent){
  __shared__ float sval[D_N];
  __shared__ float s_inv;
  int c = blockIdx.x, t = threadIdx.x, l = t & 63, w = t >> 6;
  if(w==0){                     // fused inv_en: rows [c*64, c*64+64)
    int r = c*64 + l;
    float sn = psn[r] + psn[B_N + r] + psn[2*B_N + r] + psn[3*B_N + r];
    inv_en[r] = 1.f / fmaxf(sqrtf(sn), 1e-12f);
  }
  if(c >= C_N){
    for(int d=t; d<D_N; d+=256) centnb[(size_t)c*D_N + d] = 0;  // bf16 +0 pad
    return;
  }
  float cnt = counts[c];
  float ic = 1.f / fmaxf(cnt, 1.f);
  float ss = 0.f;
  for(int d=t; d<D_N; d+=256){
    float v = cent[(size_t)c*D_N + d]*ic;
    sval[d] = v;
    ss += v*v;
  }
  ss = blockSum256(ss);
  if(t==0){
    c2raw[c] = ss;
    float inv = 1.f / fmaxf(sqrtf(ss), 1e-12f);
    c2n[c] = ss*inv*inv;
    s_inv = inv;
    if(cnt > 0.f) atomicAdd(npresent, 1u);
  }
  __syncthreads();
  float inv = s_inv;
  for(int d=t; d<D_N; d+=256){
    float v = sval[d];
    cent[(size_t)c*D_N + d] = v;
    centnb[(size_t)c*D_N + d] = bfbits(v*inv);
  }
}

// ---------------- centroid Gram (k-split 16, non-atomic partial slabs) -------
__global__ __launch_bounds__(256) void tgl_gram(const float* __restrict__ cent,
                                                float* __restrict__ gramp){
  __shared__ float at[64][36];
  __shared__ float bt[64][36];
  int t = threadIdx.x, tx = t & 15, ty = t >> 4;
  int i0 = blockIdx.x*64, j0 = blockIdx.y*64, k0 = blockIdx.z*128;
  float acc[4][4] = {};
  for(int kk=k0; kk<k0+128; kk+=32){
    __syncthreads();
#pragma unroll
    for(int u=0;u<2;u++){
      int v = t + u*256; int r = v>>3, q = (v&7)*4;
      float4 a = (i0+r < C_N) ? *(const float4*)&cent[(size_t)(i0+r)*D_N + kk + q] : make_float4(0,0,0,0);
      *(float4*)&at[r][q] = a;
      float4 b = (j0+r < C_N) ? *(const float4*)&cent[(size_t)(j0+r)*D_N + kk + q] : make_float4(0,0,0,0);
      *(float4*)&bt[r][q] = b;
    }
    __syncthreads();
#pragma unroll
    for(int kq=0;kq<8;kq++){
      float4 a[4], b[4];
#pragma unroll
      for(int i=0;i<4;i++) a[i] = *(float4*)&at[ty*4+i][kq*4];
#pragma unroll
      for(int j=0;j<4;j++) b[j] = *(float4*)&bt[tx+16*j][kq*4];
#pragma unroll
      for(int i=0;i<4;i++)
#pragma unroll
        for(int j=0;j<4;j++)
          acc[i][j] += a[i].x*b[j].x + a[i].y*b[j].y + a[i].z*b[j].z + a[i].w*b[j].w;
    }
  }
  float* slab = gramp + (size_t)blockIdx.z*65536;
#pragma unroll
  for(int i=0;i<4;i++)
#pragma unroll
    for(int j=0;j<4;j++)
      slab[(size_t)(i0+ty*4+i)*CP + (j0+tx+16*j)] = acc[i][j];
}

// ---------------- margin GEMM: 64x256 tile, 512 thr, 3-buffer counted-vmcnt --
// T3+T4: tile k+2 staged while computing k; s_waitcnt vmcnt(5) (one stage's
// 5 gloads stay in flight across the barrier). Raw s_barrier. 256 blocks=1/CU.
template<bool EBF>
__global__ __launch_bounds__(512) void tgl_margin(const unsigned short* __restrict__ ebf,
                                                  const float* __restrict__ emb,
                                                  const float* __restrict__ inv_en,
                                                  const unsigned short* __restrict__ centnb,
                                                  const int* __restrict__ labels,
                                                  const float* __restrict__ c2n,
                                                  float* __restrict__ pp){
  __shared__ __align__(16) char smem[122880];  // 3 x (A 8KB + B 32KB)
  int t = threadIdx.x, w = t>>6, l = t&63;
  int wm = w>>2, wn = w&3;                     // 8 waves: 2 (M) x 4 (N), 32x64 each
  int s0 = blockIdx.x*64;

  // hoisted per-thread staging sources + LDS byte offsets (advance by kk only)
  const unsigned short* pA;
  const unsigned short* pB[4];
  int ldsA = t*16;
  int ldsB[4];
  {
    int rowA = t>>3, ksA = t&7;
    pA = ebf + (size_t)(s0+rowA)*D_N + ((ksA ^ (rowA&7))<<3);
#pragma unroll
    for(int q=0;q<4;q++){
      int s2 = q*512 + t;
      int rowB = s2>>3, ksB = s2&7;
      pB[q] = centnb + (size_t)rowB*D_N + ((ksB ^ (rowB&7))<<3);
      ldsB[q] = 8192 + s2*16;
    }
  }
  const float* pE[2]; int ldsE[2];
  if constexpr(!EBF){
#pragma unroll
    for(int q2=0;q2<2;q2++){
      int v = q2*512 + t;
      int rowE = v>>4, kqE = v&15;
      pE[q2] = emb + (size_t)(s0+rowE)*D_N + kqE*4;
      ldsE[q2] = rowE*128 + (((kqE>>1)^(rowE&7))<<4) + (kqE&1)*8;
    }
  }

  auto stage = [&](char* dst, int kk){
#pragma unroll
    for(int q=0;q<4;q++)
      gload_lds16(pB[q] + kk, dst + ldsB[q]);
    if constexpr(EBF){
      gload_lds16(pA + kk, dst + ldsA);
    } else {
#pragma unroll
      for(int q2=0;q2<2;q2++){
        float4 f = *(const float4*)(pE[q2] + kk);
        ushort4 hb;
        hb.x=bfbits(f.x); hb.y=bfbits(f.y); hb.z=bfbits(f.z); hb.w=bfbits(f.w);
        *(ushort4*)(dst + ldsE[q2]) = hb;
      }
    }
  };

  // hoisted ds_read byte offsets: A row m at m*128 ^swizzle; B at +8192
  int baseA[2], baseB[4], xofs[2];
#pragma unroll
  for(int i=0;i<2;i++)  baseA[i]  = (wm*32 + i*16 + (l&15))*128;
#pragma unroll
  for(int jj=0;jj<4;jj++) baseB[jj] = 8192 + (wn*64 + jj*16 + (l&15))*128;
#pragma unroll
  for(int s=0;s<2;s++)  xofs[s]  = ((s*4 + (l>>4)) ^ (l&7))<<4;

  char* bR = smem;              // read
  char* bN = smem + 40960;      // next (in flight)
  char* bS = smem + 81920;      // stage target
  f32x4 acc[2][4] = {};

  stage(bR, 0);
  stage(bN, 64);
  if constexpr(EBF) asm volatile("s_waitcnt vmcnt(5)" ::: "memory");
  else              asm volatile("s_waitcnt vmcnt(0) lgkmcnt(0)" ::: "memory");
  __builtin_amdgcn_s_barrier();

  for(int ks=0; ks<32; ++ks){
    if(ks < 30) stage(bS, (ks+2)*64);
#pragma unroll
    for(int s=0;s<2;s++){
      bf16x8 af[2], bfr[4];
#pragma unroll
      for(int i=0;i<2;i++)   af[i]   = *(const bf16x8*)(bR + baseA[i]  + xofs[s]);
#pragma unroll
      for(int jj=0;jj<4;jj++) bfr[jj] = *(const bf16x8*)(bR + baseB[jj] + xofs[s]);
#pragma unroll
      for(int i=0;i<2;i++)
#pragma unroll
        for(int jj=0;jj<4;jj++)
          acc[i][jj] = __builtin_amdgcn_mfma_f32_16x16x32_bf16(af[i], bfr[jj], acc[i][jj], 0,0,0);
    }
    if constexpr(EBF){
      if(ks < 30) asm volatile("s_waitcnt vmcnt(5)" ::: "memory");
      else        asm volatile("s_waitcnt vmcnt(0)" ::: "memory");
    } else {
      asm volatile("s_waitcnt vmcnt(0) lgkmcnt(0)" ::: "memory");
    }
    __builtin_amdgcn_s_barrier();
    char* tmp = bR; bR = bN; bN = bS; bS = tmp;
  }

#pragma unroll
  for(int i=0;i<2;i++){
#pragma unroll
    for(int r=0;r<4;r++){
      int srow = s0 + wm*32 + i*16 + (l>>4)*4 + r;
      int lab = labels[srow];
      float inv = inv_en[srow];
#pragma unroll
      for(int jj=0;jj<4;jj++){
        int c = wn*64 + jj*16 + (l&15);
        if(c < C_N){
          float dot = acc[i][jj][r]*inv;
          float d2 = 1.f + c2n[c] - 2.f*dot;
          float h = 1.2f - sqrtf(fmaxf(d2, 0.f));
          if(h > 0.f) atomicAdd(&pp[(size_t)lab*C_N + c], h);
        }
      }
    }
  }
}

// ---------------- tail2: pdist-reduce + topo (expanded) + margin + finalize --
// topo sum expanded so pmax is only needed as a final scalar:
//   Sum (pd/pmax - M/maxM)^2 = S1/pmax^2 - 2*S2/(pmax*maxM) + S3/maxM^2
__global__ __launch_bounds__(256) void tgl_tail2(const float* __restrict__ gramp,
                                                 const float* __restrict__ c2raw,
                                                 const float* __restrict__ counts,
                                                 const float* __restrict__ M,
                                                 const float* __restrict__ pp,
                                                 float* __restrict__ scal,
                                                 float* __restrict__ out){
  unsigned* scal_u = (unsigned*)scal;
  float maxM = scal[3];                 // finalized in fat1 (kernel boundaries ago)
  float inv_maxM = 1.f / maxM;
  int idx = blockIdx.x*256 + threadIdx.x;
  float s1=0.f, s2=0.f, s3=0.f, c1=0.f, sm=0.f, c2=0.f;
  if(idx < C_N*C_N){
    int i = idx / C_N, j = idx % C_N;
    float g = 0.f;
#pragma unroll
    for(int s=0; s<16; s++) g += gramp[(size_t)s*65536 + (size_t)i*CP + j];
    float ps = c2raw[i] + c2raw[j] - 2.f*g;
    float pd = sqrtf(fmaxf(ps, 0.f) + 1e-12f);
    bool both = counts[i] > 0.f && counts[j] > 0.f;
    if(both) atomicMax(&scal_u[4], __float_as_uint(pd));
    float Mv = M[idx];
    if(j > i && both){ s1 = pd*pd; s2 = pd*Mv; s3 = Mv*Mv; c1 = 1.f; }
    float Mn = Mv*inv_maxM;
    if(i != j && both && Mn < 0.3f){
      sm = pp[idx] / fmaxf(counts[i], 1.f);
      c2 = 1.f;
    }
  }
  s1 = blockSum256(s1); s2 = blockSum256(s2); s3 = blockSum256(s3);
  c1 = blockSum256(c1); sm = blockSum256(sm); c2 = blockSum256(c2);
  if(threadIdx.x==0){
    atomicAdd(&scal[1], s1); atomicAdd(&scal[9], s2); atomicAdd(&scal[10], s3);
    atomicAdd(&scal[5], c1); atomicAdd(&scal[2], sm); atomicAdd(&scal[6], c2);
    __threadfence();
    unsigned old = atomicAdd(&scal_u[8], 1u);
    if(old == gridDim.x - 1){
      float S1   = atomicAdd(&scal[1], 0.f);
      float S2b  = atomicAdd(&scal[9], 0.f);
      float S3b  = atomicAdd(&scal[10], 0.f);
      float nu   = atomicAdd(&scal[5], 0.f);
      float msum = atomicAdd(&scal[2], 0.f);
      float np   = atomicAdd(&scal[6], 0.f);
      float ce   = atomicAdd(&scal[0], 0.f) / (float)B_N;
      unsigned npr = atomicAdd(&scal_u[7], 0u);
      float pmax = __uint_as_float(atomicMax(&scal_u[4], 0u));
      float ip = 1.f / pmax;
      float tsum = fmaxf(S1*ip*ip - 2.f*S2b*ip*inv_maxM + S3b*inv_maxM*inv_maxM, 0.f);
      int gate = npr >= 2u;
      float topo   = gate ? tsum / fmaxf(nu, 1.f) : 0.f;
      float margin = (gate && np > 0.f) ? msum / fmaxf(np, 1.f) : 0.f;
      out[0] = ce + 0.1f*topo + 0.05f*margin;
      out[1] = ce;
      out[2] = topo;
      out[3] = margin;
    }
  }
}

extern "C" void kernel_launch(void* const* d_in, const int* in_sizes, int n_in,
                              void* d_out, int out_size, void* d_ws, size_t ws_size,
                              hipStream_t stream){
  const float* logits = (const float*)d_in[0];
  const int*   labels = (const int*)d_in[1];
  const float* emb    = (const float*)d_in[2];
  const float* M      = (const float*)d_in[3];
  float* out = (float*)d_out;
  float* ws  = (float*)d_ws;

  float* pp     = ws + OFF_PP;
  float* scal   = ws + OFF_SCAL;
  float* counts = ws + OFF_COUNTS;
  int*   offg   = (int*)(ws + OFF_OFFG);
  int*   bh     = (int*)(ws + OFF_BH);
  int*   sorted = (int*)(ws + OFF_SORT);
  float* cent   = ws + OFF_CENT;
  float* gramp  = ws + OFF_GRAMP;
  float* c2raw  = ws + OFF_C2RAW;
  float* c2n    = ws + OFF_C2N;
  float* inv_en = ws + OFF_INVEN;
  float* psn    = ws + OFF_PSN;
  unsigned short* centnb = (unsigned short*)(ws + OFF_CENTNB);
  unsigned short* ebf    = (unsigned short*)(ws + OFF_EBF);
  unsigned* scal_u = (unsigned*)scal;

  bool use_ebf = (ws_size / sizeof(float)) >= (size_t)T2_END;

  hipMemsetAsync(d_ws, 0, (size_t)ZERO_N*sizeof(float), stream);

  tgl_cehist<<<1088, 256, 0, stream>>>(logits, labels, M, bh, scal);
  tgl_scatter<<<64, 256, 0, stream>>>(labels, bh, offg, counts, sorted);
  {
    dim3 g(C_N, 4);
    if(use_ebf) tgl_gather<true ><<<g, 256, 0, stream>>>(emb, sorted, offg, cent, psn, ebf);
    else        tgl_gather<false><<<g, 256, 0, stream>>>(emb, sorted, offg, cent, psn, ebf);
  }
  tgl_cfin<<<CP, 256, 0, stream>>>(cent, counts, psn, inv_en, centnb, c2raw, c2n, &scal_u[7]);
  {
    dim3 g(4, 4, 16);
    tgl_gram<<<g, 256, 0, stream>>>(cent, gramp);
  }
  {
    if(use_ebf) tgl_margin<true ><<<256, 512, 0, stream>>>(ebf, emb, inv_en, centnb, labels, c2n, pp);
    else        tgl_margin<false><<<256, 512, 0, stream>>>(ebf, emb, inv_en, centnb, labels, c2n, pp);
  }
  tgl_tail2<<<(C_N*C_N + 255)/256, 256, 0, stream>>>(gramp, c2raw, counts, M, pp, scal, out);
}